// Round 6
// baseline (36.861 us; speedup 1.0000x reference)
//
#include <hip/hip_runtime.h>

namespace {

constexpr int FHc = 3, FWc = 3;
constexpr int Bc = 8, Cc = 32, Hc = 32, Wc = 32, Oc = 64;
constexpr int HOc = 30, WOc = 30;
constexpr float SHIFTc = 0.1f;
constexpr int SW = 4;                     // wo-positions per block
constexpr int NX = Bc * Cc * Hc * Wc;     // 1048576 x-elements
constexpr int NK = FHc * FWc * Cc * Oc;   // 18432 (p,o) pairs
constexpr int LN_OFF = NX;                // ln region (floats)
constexpr int KT_OFF = 2 * NX;            // packed k (float2) region

// ---- kernel 1: precompute lp/ln and zip k1,k2 into float2 kt ----
__global__ __launch_bounds__(256)
void prep_kernel(const float* __restrict__ x, const float* __restrict__ k1,
                 const float* __restrict__ k2, float* __restrict__ ws)
{
    const int bid = blockIdx.x;
    if (bid < NX / 256) {
        const int t = bid * 256 + threadIdx.x;
        const float xv = x[t];
        ws[t]          = __logf(fmaxf(xv,  SHIFTc));
        ws[LN_OFF + t] = __logf(fmaxf(-xv, SHIFTc));
    } else {
        const int t = (bid - NX / 256) * 256 + threadIdx.x;
        if (t < NK) {
            float2* kt = reinterpret_cast<float2*>(ws + KT_OFF);
            kt[t] = make_float2(k1[t], k2[t]);   // k1/k2 share flat [i][j][c][o] layout
        }
    }
}

// 6-float wave-uniform row load (16B-aligned; should lower to s_load)
#define LDROW6(dst, p) do {                                              \
    const float4 _a = *reinterpret_cast<const float4*>(p);               \
    const float2 _b = *reinterpret_cast<const float2*>((p) + 4);         \
    dst[0]=_a.x; dst[1]=_a.y; dst[2]=_a.z; dst[3]=_a.w;                  \
    dst[4]=_b.x; dst[5]=_b.y; } while (0)

#define M3(m, a, b) (m) = fmaxf(fmaxf((m), (a)), (b))   // -> v_max3_f32

// ---- kernel 2: max-plus main. No staging, rows wave-uniform from ws. ----
__global__ __launch_bounds__(256, 4)   // empirical gfx950 fit: cap = 256/4 = 64 VGPR
void bipolar_main(const float* __restrict__ ws, const float* __restrict__ bias,
                  float* __restrict__ out)
{
    __shared__ float sh[4096];   // 16 KiB: cross-wave reduction buffer only

    const int tid = threadIdx.x;
    const int bid = blockIdx.x;
    const int wt  = bid & 7;               // wo-tile of 4
    const int ho  = (bid >> 3) % HOc;
    const int b   = bid / (8 * HOc);
    const int wo0 = wt * SW;
    const int o   = tid & 63;              // lane = output channel
    const int wv  = __builtin_amdgcn_readfirstlane(tid >> 6);  // force wave-uniform
    const int cbase = wv * 8;              // wave owns 8 channels

    const float2* __restrict__ kt = reinterpret_cast<const float2*>(ws + KT_OFF);

    float m11[SW], m12[SW], m21[SW], m22[SW];
    #pragma unroll
    for (int s = 0; s < SW; ++s) m11[s] = m12[s] = m21[s] = m22[s] = -1e30f;

    #pragma unroll 1
    for (int cp = 0; cp < 4; ++cp) {       // channel pairs
        const int c0 = cbase + cp * 2;
        #pragma unroll
        for (int i = 0; i < FHc; ++i) {
            // wave-uniform row pointers (lp c0, lp c0+1, ln c0, ln c0+1)
            const float* lp0 = ws + ((b * Cc + c0) * Hc + (ho + i)) * Wc + wo0;
            float rlp0[6], rlp1[6], rln0[6], rln1[6];
            LDROW6(rlp0, lp0);
            LDROW6(rlp1, lp0 + Hc * Wc);
            LDROW6(rln0, lp0 + LN_OFF);
            LDROW6(rln1, lp0 + LN_OFF + Hc * Wc);

            // packed (k1,k2) taps: 3 j-taps x 2 channels, lane-indexed by o
            const int kb = (i * FWc * Cc + c0) * Oc + o;       // float2 index, j=0
            const float2 ka0 = kt[kb],                 kb0 = kt[kb + Oc];
            const float2 ka1 = kt[kb + Cc * Oc],       kb1 = kt[kb + Cc * Oc + Oc];
            const float2 ka2 = kt[kb + 2 * Cc * Oc],   kb2 = kt[kb + 2 * Cc * Oc + Oc];

            #pragma unroll
            for (int s = 0; s < SW; ++s) {
                M3(m11[s], rlp0[s] + ka0.x, rlp0[s+1] + ka1.x);
                M3(m11[s], rlp0[s+2] + ka2.x, rlp1[s] + kb0.x);
                M3(m11[s], rlp1[s+1] + kb1.x, rlp1[s+2] + kb2.x);

                M3(m12[s], rlp0[s] + ka0.y, rlp0[s+1] + ka1.y);
                M3(m12[s], rlp0[s+2] + ka2.y, rlp1[s] + kb0.y);
                M3(m12[s], rlp1[s+1] + kb1.y, rlp1[s+2] + kb2.y);

                M3(m21[s], rln0[s] + ka0.x, rln0[s+1] + ka1.x);
                M3(m21[s], rln0[s+2] + ka2.x, rln1[s] + kb0.x);
                M3(m21[s], rln1[s+1] + kb1.x, rln1[s+2] + kb2.x);

                M3(m22[s], rln0[s] + ka0.y, rln0[s+1] + ka1.y);
                M3(m22[s], rln0[s+2] + ka2.y, rln1[s] + kb0.y);
                M3(m22[s], rln1[s+1] + kb1.y, rln1[s+2] + kb2.y);
            }
        }
    }

    // ---- cross-wave max reduction (4 waves covered 8 channels each) ----
    #pragma unroll
    for (int s = 0; s < SW; ++s) {
        sh[((wv * 4 + 0) * SW + s) * 64 + o] = m11[s];
        sh[((wv * 4 + 1) * SW + s) * 64 + o] = m12[s];
        sh[((wv * 4 + 2) * SW + s) * 64 + o] = m21[s];
        sh[((wv * 4 + 3) * SW + s) * 64 + o] = m22[s];
    }
    __syncthreads();

    // ---- finalize: wave wv owns spatial position s = wv ----
    const int s  = wv;
    const int wo = wo0 + s;
    if (wo < WOc) {
        const float bo = bias[o];
        float f[4];
        #pragma unroll
        for (int br = 0; br < 4; ++br) {
            const float v0 = sh[((0 * 4 + br) * SW + s) * 64 + o];
            const float v1 = sh[((1 * 4 + br) * SW + s) * 64 + o];
            const float v2 = sh[((2 * 4 + br) * SW + s) * 64 + o];
            const float v3 = sh[((3 * 4 + br) * SW + s) * 64 + o];
            f[br] = fmaxf(fmaxf(v0, v1), fmaxf(v2, v3));
        }
        out[((b * Oc + o) * HOc + ho) * WOc + wo] =
            __expf(f[0]) - __expf(f[1]) - __expf(f[2]) + __expf(f[3]) + bo;
    }
}

} // namespace

extern "C" void kernel_launch(void* const* d_in, const int* in_sizes, int n_in,
                              void* d_out, int out_size, void* d_ws, size_t ws_size,
                              hipStream_t stream) {
    const float* x    = (const float*)d_in[0];
    const float* k1   = (const float*)d_in[1];
    const float* k2   = (const float*)d_in[2];
    const float* bias = (const float*)d_in[3];
    float* ws         = (float*)d_ws;
    float* out        = (float*)d_out;

    const int prep_blocks = NX / 256 + (NK + 255) / 256;   // 4096 + 72
    prep_kernel<<<dim3(prep_blocks), dim3(256), 0, stream>>>(x, k1, k2, ws);

    const int main_blocks = Bc * HOc * 8;                  // 1920 (wo tiles of 4)
    bipolar_main<<<dim3(main_blocks), dim3(256), 0, stream>>>(ws, bias, out);
}